// Round 5
// baseline (402.621 us; speedup 1.0000x reference)
//
#include <hip/hip_runtime.h>
#include <hip/hip_bf16.h>
#include <stdint.h>

// VQ nearest-codebook: B=8,N=4096,C=256,K=8192
// R5: hi-only fp16 GEMM, 64x128 wave tile, BK=64 (64 MFMA per barrier-pair,
// 32 barrier-pairs/block) + int-key top-2 (6 instr/elem, 32-reg state).
// Algorithm (per-256-code top-2 records + exact fp32 margin finalize) verified R3/R4.

#define M_ROWS 32768   // B*N
#define KCODES 8192
#define CDIM   256
#define BM 128
#define BNT 256        // codes per block tile
#define BK 64
#define NSPLIT 4
#define KCHUNK 2048    // codes per chunk (blockIdx.y)
#define NTILES 8       // KCHUNK / BNT
#define KSTEPS 4       // CDIM / BK
#define NREC 32        // records per row, each covers 256 codes
#define MARGIN 0.75f   // >> hi-GEMM err (~0.32) + 2x quantization (0.125)

typedef _Float16 f16x8 __attribute__((ext_vector_type(8)));
typedef _Float16 f16x4 __attribute__((ext_vector_type(4)));
typedef float    f32x4 __attribute__((ext_vector_type(4)));

__device__ __forceinline__ unsigned umin2(unsigned a, unsigned b) { return a < b ? a : b; }
__device__ __forceinline__ unsigned umax2(unsigned a, unsigned b) { return a > b ? a : b; }

// ---------------- prep: fp16 hi (scaled by 64) + row sq-norms ----------------
__global__ void vq_prep(const float* __restrict__ x, const float* __restrict__ cb,
                        _Float16* __restrict__ xhi, _Float16* __restrict__ cbhi,
                        float* __restrict__ xsq, float* __restrict__ cbsq) {
  const int wave = threadIdx.x >> 6, lane = threadIdx.x & 63;
  const int row = blockIdx.x * 4 + wave;     // one wave per row
  const float* src;
  _Float16* dhi;
  float* dsq;
  if (row < M_ROWS) {
    src = x + (size_t)row * CDIM;  dhi = xhi + (size_t)row * CDIM;  dsq = xsq + row;
  } else {
    const int r = row - M_ROWS;
    src = cb + (size_t)r * CDIM;   dhi = cbhi + (size_t)r * CDIM;   dsq = cbsq + r;
  }
  const float4 v = *(const float4*)(src + lane * 4);
  f16x4 h;
  h[0] = (_Float16)(v.x * 64.0f); h[1] = (_Float16)(v.y * 64.0f);
  h[2] = (_Float16)(v.z * 64.0f); h[3] = (_Float16)(v.w * 64.0f);
  *(f16x4*)(dhi + lane * 4) = h;
  float s = v.x * v.x + v.y * v.y + v.z * v.z + v.w * v.w;
  #pragma unroll
  for (int off = 32; off > 0; off >>= 1) s += __shfl_down(s, off, 64);
  if (lane == 0) *dsq = s;
}

// ---------------- pass1: hi GEMM + per-subchunk top-2 int-key records ----------------
__device__ __forceinline__ void gl16(const _Float16* g, _Float16* l) {
  __builtin_amdgcn_global_load_lds(
      (const __attribute__((address_space(1))) unsigned int*)g,
      (__attribute__((address_space(3))) unsigned int*)l, 16, 0, 0);
}

__global__ __launch_bounds__(256, 2) void vq_pass1(
    const _Float16* __restrict__ xhi, const _Float16* __restrict__ cbhi,
    const float* __restrict__ cbsq, uint2* __restrict__ srec) {
  const int tid  = threadIdx.x;
  const int wave = tid >> 6, lane = tid & 63;
  const int quad = lane >> 4, l15 = lane & 15;
  const int mbase  = blockIdx.x * BM;
  const int cbase0 = blockIdx.y * KCHUNK;
  const int wrow = (wave >> 1) * 64;    // row half
  const int wcol = (wave & 1) * 128;    // col half

  __shared__ alignas(16) _Float16 sA[BM * BK];    // 16 KB
  __shared__ alignas(16) _Float16 sB[BNT * BK];   // 32 KB

  // staging: row stride 128B = 8x16B slots; LDS(row,s) = Global(row, s^(row&7))
  const int r8 = lane >> 3, s8 = lane & 7;
  const int scol = ((s8 ^ r8) & 7) << 3;          // r8<8 so r8&7==r8
  // frag read de-swizzle base (kc handled via XOR inside loop)
  const int fsw = l15 & 7;

  unsigned k1[4][4], k2[4][4];

  for (int nt = 0; nt < NTILES; ++nt) {
    const int cb0 = cbase0 + nt * BNT;
    if ((nt & 1) == 0) {   // open subchunk (2 nt x 128 wave-cols = 256 codes)
      #pragma unroll
      for (int mf = 0; mf < 4; ++mf)
        #pragma unroll
        for (int i = 0; i < 4; ++i) { k1[mf][i] = 0x7fffffffu; k2[mf][i] = 0x7fffffffu; }
    }

    f32x4 acc[4][8];
    #pragma unroll
    for (int mf = 0; mf < 4; ++mf)
      #pragma unroll
      for (int nf = 0; nf < 8; ++nf) {
        f32x4 z = {0.0f, 0.0f, 0.0f, 0.0f};
        acc[mf][nf] = z;
      }

    for (int ks = 0; ks < KSTEPS; ++ks) {
      const int kofs = ks * BK;
      __syncthreads();
      // A: 16 slices of 8 rows, 4 per wave
      #pragma unroll
      for (int t = 0; t < 4; ++t) {
        const int rows = (wave * 4 + t) * 8;
        gl16(xhi + (size_t)(mbase + rows + r8) * CDIM + kofs + scol, sA + rows * BK);
      }
      // B: 32 slices, 8 per wave
      #pragma unroll
      for (int t = 0; t < 8; ++t) {
        const int rows = (wave * 8 + t) * 8;
        gl16(cbhi + (size_t)(cb0 + rows + r8) * CDIM + kofs + scol, sB + rows * BK);
      }
      __syncthreads();

      #pragma unroll
      for (int kc = 0; kc < 2; ++kc) {
        const int slot = ((quad + kc * 4) ^ fsw) << 3;   // element offset in row
        f16x8 ah[4];
        #pragma unroll
        for (int mf = 0; mf < 4; ++mf)
          ah[mf] = *(const f16x8*)(sA + (wrow + mf * 16 + l15) * BK + slot);
        #pragma unroll
        for (int nf = 0; nf < 8; ++nf) {
          const f16x8 bh = *(const f16x8*)(sB + (wcol + nf * 16 + l15) * BK + slot);
          #pragma unroll
          for (int mf = 0; mf < 4; ++mf)
            acc[mf][nf] = __builtin_amdgcn_mfma_f32_16x16x32_f16(ah[mf], bh, acc[mf][nf], 0, 0, 0);
        }
      }
    }

    // int-key top-2 insert: key = (uint)(16*v + 32768) << 13 | col
    // v = cbsq - 2*dot; acc = 4096*dot => 16*v = (16*cbsq+32768) - acc/128
    #pragma unroll
    for (int nf = 0; nf < 8; ++nf) {
      const int col = cb0 + wcol + nf * 16 + l15;   // C/D: col = lane&15
      const float cq16 = fmaf(cbsq[col], 16.0f, 32768.0f);
      #pragma unroll
      for (int mf = 0; mf < 4; ++mf)
        #pragma unroll
        for (int i = 0; i < 4; ++i) {
          const float kf = fmaf(acc[mf][nf][i], -0.0078125f, cq16);
          const unsigned key = ((unsigned)kf << 13) | (unsigned)col;
          k2[mf][i] = umin2(k2[mf][i], umax2(k1[mf][i], key));
          k1[mf][i] = umin2(k1[mf][i], key);
        }
    }

    if (nt & 1) {   // close subchunk: 16-lane top-2 merge, store record
      const int g = blockIdx.y * 8 + (nt >> 1) * 2 + (wave & 1);  // 0..31
      #pragma unroll
      for (int mf = 0; mf < 4; ++mf)
        #pragma unroll
        for (int i = 0; i < 4; ++i) {
          unsigned a1 = k1[mf][i], a2 = k2[mf][i];
          #pragma unroll
          for (int m = 1; m <= 8; m <<= 1) {
            const unsigned o1 = (unsigned)__shfl_xor((int)a1, m, 64);
            const unsigned o2 = (unsigned)__shfl_xor((int)a2, m, 64);
            a2 = umin2(umin2(a2, o2), umax2(a1, o1));
            a1 = umin2(a1, o1);
          }
          if (l15 == 0) {
            const int rl = wrow + mf * 16 + quad * 4 + i;   // C/D row
            uint2 r; r.x = a1; r.y = a2;
            srec[(size_t)(mbase + rl) * NREC + g] = r;
          }
        }
    }
  }
}

// ---------------- finalize: exact fp32 dots for margin candidates ----------------
__global__ void vq_finalize(const float* __restrict__ x, const float* __restrict__ cb,
                            const float* __restrict__ xsq, const float* __restrict__ cbsq,
                            const uint2* __restrict__ srec,
                            float* __restrict__ outIdx, float* __restrict__ outDist,
                            float* __restrict__ codes) {
  const int wave = threadIdx.x >> 6, lane = threadIdx.x & 63;
  const int row = blockIdx.x * 4 + wave;    // one wave per row
  uint2 rec;
  if (lane < NREC) rec = srec[(size_t)row * NREC + lane];
  else { rec.x = 0x7fffffffu; rec.y = 0x7fffffffu; }
  const float v1 = (float)(rec.x >> 13) * 0.0625f - 2048.0f;
  const float v2 = (float)(rec.y >> 13) * 0.0625f - 2048.0f;
  const int c1 = (int)(rec.x & 8191u);
  const int c2 = (int)(rec.y & 8191u);

  float gm = v1;
  #pragma unroll
  for (int m = 1; m <= 32; m <<= 1) gm = fminf(gm, __shfl_xor(gm, m, 64));
  const float thr = gm + MARGIN;
  unsigned long long mask1 = __ballot(v1 <= thr);
  unsigned long long mask2 = __ballot(v2 <= thr);

  const float4 xv = *(const float4*)(x + (size_t)row * CDIM + lane * 4);
  const float xq = xsq[row];
  float best = __builtin_inff(); int bidx = 1 << 30;

  #pragma unroll
  for (int pass = 0; pass < 2; ++pass) {
    unsigned long long m = pass ? mask2 : mask1;
    const int fi = pass ? c2 : c1;
    while (m) {
      const int g = __builtin_ctzll((long long)m); m &= m - 1;
      const int ci = __shfl(fi, g, 64);
      const float4 cv = *(const float4*)(cb + (size_t)ci * CDIM + lane * 4);
      float s = xv.x * cv.x + xv.y * cv.y + xv.z * cv.z + xv.w * cv.w;
      #pragma unroll
      for (int mm = 1; mm <= 32; mm <<= 1) s += __shfl_xor(s, mm, 64);
      const float dist = xq + cbsq[ci] - 2.0f * s;
      if (dist < best || (dist == best && ci < bidx)) { best = dist; bidx = ci; }
    }
  }

  if (lane == 0) { outIdx[row] = (float)bidx; outDist[row] = best; }
  const float4 cw = *(const float4*)(cb + (size_t)bidx * CDIM + lane * 4);
  *(float4*)(codes + (size_t)row * CDIM + lane * 4) = cw;
}

extern "C" void kernel_launch(void* const* d_in, const int* in_sizes, int n_in,
                              void* d_out, int out_size, void* d_ws, size_t ws_size,
                              hipStream_t stream) {
  const float* x  = (const float*)d_in[0];   // [8,4096,256] fp32
  const float* cb = (const float*)d_in[1];   // [8192,256] fp32
  float* out = (float*)d_out;                // codes | idx | dist

  char* w = (char*)d_ws;                     // ~29.2 MB
  _Float16* xhi  = (_Float16*)(w);                 // 16 MB
  _Float16* cbhi = (_Float16*)(w + 16777216);      //  4 MB
  float*    xsq  = (float*)   (w + 20971520);      // 128 KB
  float*    cbsq = (float*)   (w + 21102592);      //  32 KB
  uint2*    srec = (uint2*)   (w + 21135360);      //  8 MB (32768*32*8B)

  vq_prep<<<(M_ROWS + KCODES) / 4, 256, 0, stream>>>(x, cb, xhi, cbhi, xsq, cbsq);
  vq_pass1<<<dim3(M_ROWS / BM, NSPLIT), 256, 0, stream>>>(xhi, cbhi, cbsq, srec);
  vq_finalize<<<M_ROWS / 4, 256, 0, stream>>>(x, cb, xsq, cbsq, srec,
                                              out + 8388608, out + 8421376, out);
}

// Round 6
// 398.837 us; speedup vs baseline: 1.0095x; 1.0095x over previous
//
#include <hip/hip_runtime.h>
#include <hip/hip_bf16.h>
#include <stdint.h>

// VQ nearest-codebook: B=8,N=4096,C=256,K=8192
// R6: R2's proven-no-spill GEMM structure (BK=32, 64x128 wave tile, 128x256 block,
// measured 56% MfmaUtil / 0 conflicts / 0 spill), hi-only fp16 (1/3 MFMA) +
// 6-instr int-key top-2 per 256-code subchunk + exact fp32 margin finalize
// (record/finalize pipeline verified exact in R3/R4/R5: absmax=0).
// R5 failed: BK=64 addressing + acc[4][8] > 256 unified regs -> 82MB spill.

#define M_ROWS 32768   // B*N
#define KCODES 8192
#define CDIM   256
#define BM 128
#define BNT 256        // codes per block tile
#define BK 32
#define NSPLIT 2
#define KCHUNK 4096    // codes per chunk (blockIdx.y)
#define NTILES 16      // KCHUNK / BNT
#define KSTEPS 8       // CDIM / BK
#define NREC 32        // records per row, each covers 256 codes
#define MARGIN 0.75f   // >> hi-GEMM err (~0.32) + 2x key quantization (0.125)

typedef _Float16 f16x8 __attribute__((ext_vector_type(8)));
typedef _Float16 f16x4 __attribute__((ext_vector_type(4)));
typedef float    f32x4 __attribute__((ext_vector_type(4)));

__device__ __forceinline__ unsigned umin2(unsigned a, unsigned b) { return a < b ? a : b; }
__device__ __forceinline__ unsigned umax2(unsigned a, unsigned b) { return a > b ? a : b; }

// ---------------- prep: fp16 hi (scaled by 64) + row sq-norms ----------------
__global__ void vq_prep(const float* __restrict__ x, const float* __restrict__ cb,
                        _Float16* __restrict__ xhi, _Float16* __restrict__ cbhi,
                        float* __restrict__ xsq, float* __restrict__ cbsq) {
  const int wave = threadIdx.x >> 6, lane = threadIdx.x & 63;
  const int row = blockIdx.x * 4 + wave;     // one wave per row
  const float* src;
  _Float16* dhi;
  float* dsq;
  if (row < M_ROWS) {
    src = x + (size_t)row * CDIM;  dhi = xhi + (size_t)row * CDIM;  dsq = xsq + row;
  } else {
    const int r = row - M_ROWS;
    src = cb + (size_t)r * CDIM;   dhi = cbhi + (size_t)r * CDIM;   dsq = cbsq + r;
  }
  const float4 v = *(const float4*)(src + lane * 4);
  f16x4 h;
  h[0] = (_Float16)(v.x * 64.0f); h[1] = (_Float16)(v.y * 64.0f);
  h[2] = (_Float16)(v.z * 64.0f); h[3] = (_Float16)(v.w * 64.0f);
  *(f16x4*)(dhi + lane * 4) = h;
  float s = v.x * v.x + v.y * v.y + v.z * v.z + v.w * v.w;
  #pragma unroll
  for (int off = 32; off > 0; off >>= 1) s += __shfl_down(s, off, 64);
  if (lane == 0) *dsq = s;
}

// ---------------- pass1: hi GEMM + per-subchunk top-2 int-key records ----------------
__device__ __forceinline__ void gl16(const _Float16* g, _Float16* l) {
  __builtin_amdgcn_global_load_lds(
      (const __attribute__((address_space(1))) unsigned int*)g,
      (__attribute__((address_space(3))) unsigned int*)l, 16, 0, 0);
}

__global__ __launch_bounds__(256, 2) void vq_pass1(
    const _Float16* __restrict__ xhi, const _Float16* __restrict__ cbhi,
    const float* __restrict__ cbsq, uint2* __restrict__ srec) {
  const int tid  = threadIdx.x;
  const int wave = tid >> 6, lane = tid & 63;
  const int quad = lane >> 4, l15 = lane & 15;
  const int mbase  = blockIdx.x * BM;
  const int cbase0 = blockIdx.y * KCHUNK;
  const int wrow = (wave >> 1) * 64;    // row half
  const int wcol = (wave & 1) * 128;    // col half

  __shared__ alignas(16) _Float16 sA[BM * BK];    //  8 KB
  __shared__ alignas(16) _Float16 sB[BNT * BK];   // 16 KB

  // R2's measured-zero-conflict XOR swizzle (row stride 64B = 4x16B slots)
  const int srl  = lane >> 2;
  const int scol = (((lane & 3) ^ ((lane >> 3) & 3)) << 3);
  const int fcol = ((quad ^ ((l15 >> 1) & 3)) << 3);

  unsigned k1[4][4], k2[4][4];

  for (int nt = 0; nt < NTILES; ++nt) {
    const int cb0 = cbase0 + nt * BNT;
    if ((nt & 1) == 0) {   // open subchunk (2 nt x 128 wave-cols = 256 codes)
      #pragma unroll
      for (int mf = 0; mf < 4; ++mf)
        #pragma unroll
        for (int i = 0; i < 4; ++i) { k1[mf][i] = 0x7fffffffu; k2[mf][i] = 0x7fffffffu; }
    }

    f32x4 acc[4][8];
    #pragma unroll
    for (int mf = 0; mf < 4; ++mf)
      #pragma unroll
      for (int nf = 0; nf < 8; ++nf) {
        f32x4 z = {0.0f, 0.0f, 0.0f, 0.0f};
        acc[mf][nf] = z;
      }

    for (int ks = 0; ks < KSTEPS; ++ks) {
      const int kofs = ks * BK;
      __syncthreads();
      // A: 8 slices of 16 rows -> 2 per wave
      #pragma unroll
      for (int t = 0; t < 2; ++t) {
        const int rb = wave * 32 + t * 16;
        gl16(xhi + (size_t)(mbase + rb + srl) * CDIM + kofs + scol, sA + rb * BK);
      }
      // B: 16 slices -> 4 per wave
      #pragma unroll
      for (int t = 0; t < 4; ++t) {
        const int rb = wave * 64 + t * 16;
        gl16(cbhi + (size_t)(cb0 + rb + srl) * CDIM + kofs + scol, sB + rb * BK);
      }
      __syncthreads();

      f16x8 ah[4];
      #pragma unroll
      for (int mf = 0; mf < 4; ++mf)
        ah[mf] = *(const f16x8*)(sA + (wrow + mf * 16 + l15) * BK + fcol);
      #pragma unroll
      for (int nf = 0; nf < 8; ++nf) {
        const f16x8 bh = *(const f16x8*)(sB + (wcol + nf * 16 + l15) * BK + fcol);
        #pragma unroll
        for (int mf = 0; mf < 4; ++mf)
          acc[mf][nf] = __builtin_amdgcn_mfma_f32_16x16x32_f16(ah[mf], bh, acc[mf][nf], 0, 0, 0);
      }
    }

    // int-key top-2 insert: key = (uint)(16*v + 32768) << 13 | col
    // v = cbsq - 2*dot; acc = 4096*dot => 16*v = (16*cbsq+32768) - acc/128
    #pragma unroll
    for (int nf = 0; nf < 8; ++nf) {
      const int col = cb0 + wcol + nf * 16 + l15;   // C/D: col = lane&15
      const float cq16 = fmaf(cbsq[col], 16.0f, 32768.0f);
      #pragma unroll
      for (int mf = 0; mf < 4; ++mf)
        #pragma unroll
        for (int i = 0; i < 4; ++i) {
          const float kf = fmaf(acc[mf][nf][i], -0.0078125f, cq16);
          const unsigned key = ((unsigned)kf << 13) | (unsigned)col;
          k2[mf][i] = umin2(k2[mf][i], umax2(k1[mf][i], key));
          k1[mf][i] = umin2(k1[mf][i], key);
        }
    }

    if (nt & 1) {   // close subchunk: 16-lane top-2 butterfly merge, store record
      const int g = blockIdx.y * 16 + (nt >> 1) * 2 + (wave & 1);  // 0..31
      #pragma unroll
      for (int mf = 0; mf < 4; ++mf)
        #pragma unroll
        for (int i = 0; i < 4; ++i) {
          unsigned a1 = k1[mf][i], a2 = k2[mf][i];
          #pragma unroll
          for (int m = 1; m <= 8; m <<= 1) {
            const unsigned o1 = (unsigned)__shfl_xor((int)a1, m, 64);
            const unsigned o2 = (unsigned)__shfl_xor((int)a2, m, 64);
            a2 = umin2(umin2(a2, o2), umax2(a1, o1));
            a1 = umin2(a1, o1);
          }
          if (l15 == 0) {
            const int rl = wrow + mf * 16 + quad * 4 + i;   // C/D row
            uint2 r; r.x = a1; r.y = a2;
            srec[(size_t)(mbase + rl) * NREC + g] = r;
          }
        }
    }
  }
}

// ---------------- finalize: exact fp32 dots for margin candidates ----------------
__global__ void vq_finalize(const float* __restrict__ x, const float* __restrict__ cb,
                            const float* __restrict__ xsq, const float* __restrict__ cbsq,
                            const uint2* __restrict__ srec,
                            float* __restrict__ outIdx, float* __restrict__ outDist,
                            float* __restrict__ codes) {
  const int wave = threadIdx.x >> 6, lane = threadIdx.x & 63;
  const int row = blockIdx.x * 4 + wave;    // one wave per row
  uint2 rec;
  if (lane < NREC) rec = srec[(size_t)row * NREC + lane];
  else { rec.x = 0x7fffffffu; rec.y = 0x7fffffffu; }
  const float v1 = (float)(rec.x >> 13) * 0.0625f - 2048.0f;
  const float v2 = (float)(rec.y >> 13) * 0.0625f - 2048.0f;
  const int c1 = (int)(rec.x & 8191u);
  const int c2 = (int)(rec.y & 8191u);

  float gm = v1;
  #pragma unroll
  for (int m = 1; m <= 32; m <<= 1) gm = fminf(gm, __shfl_xor(gm, m, 64));
  const float thr = gm + MARGIN;
  unsigned long long mask1 = __ballot(v1 <= thr);
  unsigned long long mask2 = __ballot(v2 <= thr);

  const float4 xv = *(const float4*)(x + (size_t)row * CDIM + lane * 4);
  const float xq = xsq[row];
  float best = __builtin_inff(); int bidx = 1 << 30;

  #pragma unroll
  for (int pass = 0; pass < 2; ++pass) {
    unsigned long long m = pass ? mask2 : mask1;
    const int fi = pass ? c2 : c1;
    while (m) {
      const int g = __builtin_ctzll((long long)m); m &= m - 1;
      const int ci = __shfl(fi, g, 64);
      const float4 cv = *(const float4*)(cb + (size_t)ci * CDIM + lane * 4);
      float s = xv.x * cv.x + xv.y * cv.y + xv.z * cv.z + xv.w * cv.w;
      #pragma unroll
      for (int mm = 1; mm <= 32; mm <<= 1) s += __shfl_xor(s, mm, 64);
      const float dist = xq + cbsq[ci] - 2.0f * s;
      if (dist < best || (dist == best && ci < bidx)) { best = dist; bidx = ci; }
    }
  }

  if (lane == 0) { outIdx[row] = (float)bidx; outDist[row] = best; }
  const float4 cw = *(const float4*)(cb + (size_t)bidx * CDIM + lane * 4);
  *(float4*)(codes + (size_t)row * CDIM + lane * 4) = cw;
}

extern "C" void kernel_launch(void* const* d_in, const int* in_sizes, int n_in,
                              void* d_out, int out_size, void* d_ws, size_t ws_size,
                              hipStream_t stream) {
  const float* x  = (const float*)d_in[0];   // [8,4096,256] fp32
  const float* cb = (const float*)d_in[1];   // [8192,256] fp32
  float* out = (float*)d_out;                // codes | idx | dist

  char* w = (char*)d_ws;                     // ~29.2 MB
  _Float16* xhi  = (_Float16*)(w);                 // 16 MB
  _Float16* cbhi = (_Float16*)(w + 16777216);      //  4 MB
  float*    xsq  = (float*)   (w + 20971520);      // 128 KB
  float*    cbsq = (float*)   (w + 21102592);      //  32 KB
  uint2*    srec = (uint2*)   (w + 21135360);      //  8 MB (32768*32*8B)

  vq_prep<<<(M_ROWS + KCODES) / 4, 256, 0, stream>>>(x, cb, xhi, cbhi, xsq, cbsq);
  vq_pass1<<<dim3(M_ROWS / BM, NSPLIT), 256, 0, stream>>>(xhi, cbhi, cbsq, srec);
  vq_finalize<<<M_ROWS / 4, 256, 0, stream>>>(x, cb, xsq, cbsq, srec,
                                              out + 8388608, out + 8421376, out);
}

// Round 7
// 307.142 us; speedup vs baseline: 1.3109x; 1.2985x over previous
//
#include <hip/hip_runtime.h>
#include <hip/hip_bf16.h>
#include <stdint.h>

// VQ nearest-codebook: B=8,N=4096,C=256,K=8192
// R7: A-tile LDS-resident (BM=256, full K, staged ONCE) + streamed B (each block
// reads each B element exactly once; 2MB cb chunk stays hot in per-XCD L2).
// R4/R6 plateau at ~315us was L2-miss restaging (FETCH 308MB vs 20MB footprint),
// not spill (47MB write = srec 64B-line amplification of 8B stores).
// hi-only fp16 GEMM + int-key top-2 records + exact fp32 margin finalize
// (record/finalize pipeline verified exact R3-R6: absmax=0 every round).

#define M_ROWS 32768   // B*N
#define KCODES 8192
#define CDIM   256
#define BM 256         // rows per block (A resident: 256x256 fp16 = 128 KB LDS)
#define BNT 256        // codes per B tile
#define BK 32
#define NSPLIT 2
#define KCHUNK 4096    // codes per chunk (blockIdx.y)
#define NTILES 16      // KCHUNK / BNT
#define KSTEPS 8       // CDIM / BK
#define NREC 32        // records per row (each = top-2 over a 256-code subset)
#define MARGIN 0.75f   // >> hi-GEMM err (~0.32) + 2x key quantization (0.125)

typedef _Float16 f16x8 __attribute__((ext_vector_type(8)));
typedef _Float16 f16x4 __attribute__((ext_vector_type(4)));
typedef float    f32x4 __attribute__((ext_vector_type(4)));

__device__ __forceinline__ unsigned umin2(unsigned a, unsigned b) { return a < b ? a : b; }
__device__ __forceinline__ unsigned umax2(unsigned a, unsigned b) { return a > b ? a : b; }

// ---------------- prep: fp16 hi (scaled by 64) + row sq-norms ----------------
__global__ void vq_prep(const float* __restrict__ x, const float* __restrict__ cb,
                        _Float16* __restrict__ xhi, _Float16* __restrict__ cbhi,
                        float* __restrict__ xsq, float* __restrict__ cbsq) {
  const int wave = threadIdx.x >> 6, lane = threadIdx.x & 63;
  const int row = blockIdx.x * 4 + wave;     // one wave per row
  const float* src;
  _Float16* dhi;
  float* dsq;
  if (row < M_ROWS) {
    src = x + (size_t)row * CDIM;  dhi = xhi + (size_t)row * CDIM;  dsq = xsq + row;
  } else {
    const int r = row - M_ROWS;
    src = cb + (size_t)r * CDIM;   dhi = cbhi + (size_t)r * CDIM;   dsq = cbsq + r;
  }
  const float4 v = *(const float4*)(src + lane * 4);
  f16x4 h;
  h[0] = (_Float16)(v.x * 64.0f); h[1] = (_Float16)(v.y * 64.0f);
  h[2] = (_Float16)(v.z * 64.0f); h[3] = (_Float16)(v.w * 64.0f);
  *(f16x4*)(dhi + lane * 4) = h;
  float s = v.x * v.x + v.y * v.y + v.z * v.z + v.w * v.w;
  #pragma unroll
  for (int off = 32; off > 0; off >>= 1) s += __shfl_down(s, off, 64);
  if (lane == 0) *dsq = s;
}

// ---------------- pass1: A-resident hi GEMM + top-2 int-key records ----------------
__device__ __forceinline__ void gl16(const _Float16* g, _Float16* l) {
  __builtin_amdgcn_global_load_lds(
      (const __attribute__((address_space(1))) unsigned int*)g,
      (__attribute__((address_space(3))) unsigned int*)l, 16, 0, 0);
}

__global__ __launch_bounds__(512, 2) void vq_pass1(
    const _Float16* __restrict__ xhi, const _Float16* __restrict__ cbhi,
    const float* __restrict__ cbsq, uint2* __restrict__ srec) {
  extern __shared__ char smem[];
  _Float16* sA = (_Float16*)smem;                   // 256 x 256 fp16 = 128 KB
  _Float16* sB = (_Float16*)(smem + BM * CDIM * 2); // 256 x 32  fp16 =  16 KB

  const int tid  = threadIdx.x;
  const int wave = tid >> 6, lane = tid & 63;
  const int quad = lane >> 4, l15 = lane & 15;
  const int mbase  = blockIdx.x * BM;
  const int cbase0 = blockIdx.y * KCHUNK;
  const int wrow = (wave >> 1) * 64;    // 4 row groups x 64
  const int wcol = (wave & 1) * 128;    // 2 col halves x 128

  // ---- stage A once: row stride 512B = 32 x 16B slots, slot ^= row&7 swizzle.
  // Each gl16 covers 2 rows (64 lanes x 16B); 16 instrs per wave.
  {
    const int ar = lane >> 5;            // row within pair
    const int as = lane & 31;            // 16B slot
    #pragma unroll
    for (int t = 0; t < 16; ++t) {
      const int rb  = (wave * 16 + t) * 2;
      const int row = rb + ar;
      const int slot = as ^ (row & 7);
      gl16(xhi + (size_t)(mbase + row) * CDIM + slot * 8, sA + rb * CDIM);
    }
  }

  // B staging geometry (R2's measured-zero-conflict pattern): row stride 64B.
  const int srl  = lane >> 2;
  const int scol = (((lane & 3) ^ ((lane >> 3) & 3)) << 3);
  const int fcol = ((quad ^ ((l15 >> 1) & 3)) << 3);
  const int asw  = l15 & 7;             // A frag de-swizzle

  unsigned k1[4][4], k2[4][4];

  for (int nt = 0; nt < NTILES; ++nt) {
    const int cb0 = cbase0 + nt * BNT;
    if ((nt & 1) == 0) {   // open subchunk (2 nt x 128 wave-cols = 256 codes)
      #pragma unroll
      for (int mf = 0; mf < 4; ++mf)
        #pragma unroll
        for (int i = 0; i < 4; ++i) { k1[mf][i] = 0x7fffffffu; k2[mf][i] = 0x7fffffffu; }
    }

    f32x4 acc[4][8];
    #pragma unroll
    for (int mf = 0; mf < 4; ++mf)
      #pragma unroll
      for (int nf = 0; nf < 8; ++nf) {
        f32x4 z = {0.0f, 0.0f, 0.0f, 0.0f};
        acc[mf][nf] = z;
      }

    for (int ks = 0; ks < KSTEPS; ++ks) {
      const int kofs = ks * BK;
      __syncthreads();   // prior ks frag reads done (also covers first-A staging)
      // B: 16 slices of 16 rows -> 2 per wave
      #pragma unroll
      for (int t = 0; t < 2; ++t) {
        const int rb = wave * 32 + t * 16;
        gl16(cbhi + (size_t)(cb0 + rb + srl) * CDIM + kofs + scol, sB + rb * BK);
      }
      __syncthreads();   // staged data visible

      f16x8 ah[4];
      #pragma unroll
      for (int mf = 0; mf < 4; ++mf) {
        const int arow = wrow + mf * 16 + l15;
        const int aslot = (ks * 4 + quad) ^ asw;       // 16B slot in resident A
        ah[mf] = *(const f16x8*)(sA + arow * CDIM + aslot * 8);
      }
      #pragma unroll
      for (int nf = 0; nf < 8; ++nf) {
        const f16x8 bh = *(const f16x8*)(sB + (wcol + nf * 16 + l15) * BK + fcol);
        #pragma unroll
        for (int mf = 0; mf < 4; ++mf)
          acc[mf][nf] = __builtin_amdgcn_mfma_f32_16x16x32_f16(ah[mf], bh, acc[mf][nf], 0, 0, 0);
      }
    }

    // int-key top-2 insert: key = (uint)(16*v + 32768) << 13 | col
    // v = cbsq - 2*dot; acc = 4096*dot => 16*v = (16*cbsq+32768) - acc/128
    #pragma unroll
    for (int nf = 0; nf < 8; ++nf) {
      const int col = cb0 + wcol + nf * 16 + l15;   // C/D: col = lane&15
      const float cq16 = fmaf(cbsq[col], 16.0f, 32768.0f);
      #pragma unroll
      for (int mf = 0; mf < 4; ++mf)
        #pragma unroll
        for (int i = 0; i < 4; ++i) {
          const float kf = fmaf(acc[mf][nf][i], -0.0078125f, cq16);
          const unsigned key = ((unsigned)kf << 13) | (unsigned)col;
          k2[mf][i] = umin2(k2[mf][i], umax2(k1[mf][i], key));
          k1[mf][i] = umin2(k1[mf][i], key);
        }
    }

    if (nt & 1) {   // close subchunk: 16-lane top-2 butterfly merge, store record
      const int g = blockIdx.y * 16 + (nt >> 1) * 2 + (wave & 1);  // 0..31
      #pragma unroll
      for (int mf = 0; mf < 4; ++mf)
        #pragma unroll
        for (int i = 0; i < 4; ++i) {
          unsigned a1 = k1[mf][i], a2 = k2[mf][i];
          #pragma unroll
          for (int m = 1; m <= 8; m <<= 1) {
            const unsigned o1 = (unsigned)__shfl_xor((int)a1, m, 64);
            const unsigned o2 = (unsigned)__shfl_xor((int)a2, m, 64);
            a2 = umin2(umin2(a2, o2), umax2(a1, o1));
            a1 = umin2(a1, o1);
          }
          if (l15 == 0) {
            const int rl = wrow + mf * 16 + quad * 4 + i;   // C/D row (0..255)
            uint2 r; r.x = a1; r.y = a2;
            srec[(size_t)(mbase + rl) * NREC + g] = r;
          }
        }
    }
  }
}

// ---------------- finalize: exact fp32 dots for margin candidates ----------------
__global__ void vq_finalize(const float* __restrict__ x, const float* __restrict__ cb,
                            const float* __restrict__ xsq, const float* __restrict__ cbsq,
                            const uint2* __restrict__ srec,
                            float* __restrict__ outIdx, float* __restrict__ outDist,
                            float* __restrict__ codes) {
  const int wave = threadIdx.x >> 6, lane = threadIdx.x & 63;
  const int row = blockIdx.x * 4 + wave;    // one wave per row
  uint2 rec;
  if (lane < NREC) rec = srec[(size_t)row * NREC + lane];
  else { rec.x = 0x7fffffffu; rec.y = 0x7fffffffu; }
  const float v1 = (float)(rec.x >> 13) * 0.0625f - 2048.0f;
  const float v2 = (float)(rec.y >> 13) * 0.0625f - 2048.0f;
  const int c1 = (int)(rec.x & 8191u);
  const int c2 = (int)(rec.y & 8191u);

  float gm = v1;
  #pragma unroll
  for (int m = 1; m <= 32; m <<= 1) gm = fminf(gm, __shfl_xor(gm, m, 64));
  const float thr = gm + MARGIN;
  unsigned long long mask1 = __ballot(v1 <= thr);
  unsigned long long mask2 = __ballot(v2 <= thr);

  const float4 xv = *(const float4*)(x + (size_t)row * CDIM + lane * 4);
  const float xq = xsq[row];
  float best = __builtin_inff(); int bidx = 1 << 30;

  #pragma unroll
  for (int pass = 0; pass < 2; ++pass) {
    unsigned long long m = pass ? mask2 : mask1;
    const int fi = pass ? c2 : c1;
    while (m) {
      const int g = __builtin_ctzll((long long)m); m &= m - 1;
      const int ci = __shfl(fi, g, 64);
      const float4 cv = *(const float4*)(cb + (size_t)ci * CDIM + lane * 4);
      float s = xv.x * cv.x + xv.y * cv.y + xv.z * cv.z + xv.w * cv.w;
      #pragma unroll
      for (int mm = 1; mm <= 32; mm <<= 1) s += __shfl_xor(s, mm, 64);
      const float dist = xq + cbsq[ci] - 2.0f * s;
      if (dist < best || (dist == best && ci < bidx)) { best = dist; bidx = ci; }
    }
  }

  if (lane == 0) { outIdx[row] = (float)bidx; outDist[row] = best; }
  const float4 cw = *(const float4*)(cb + (size_t)bidx * CDIM + lane * 4);
  *(float4*)(codes + (size_t)row * CDIM + lane * 4) = cw;
}

extern "C" void kernel_launch(void* const* d_in, const int* in_sizes, int n_in,
                              void* d_out, int out_size, void* d_ws, size_t ws_size,
                              hipStream_t stream) {
  const float* x  = (const float*)d_in[0];   // [8,4096,256] fp32
  const float* cb = (const float*)d_in[1];   // [8192,256] fp32
  float* out = (float*)d_out;                // codes | idx | dist

  char* w = (char*)d_ws;                     // ~29.2 MB
  _Float16* xhi  = (_Float16*)(w);                 // 16 MB
  _Float16* cbhi = (_Float16*)(w + 16777216);      //  4 MB
  float*    xsq  = (float*)   (w + 20971520);      // 128 KB
  float*    cbsq = (float*)   (w + 21102592);      //  32 KB
  uint2*    srec = (uint2*)   (w + 21135360);      //  8 MB (32768*32*8B)

  vq_prep<<<(M_ROWS + KCODES) / 4, 256, 0, stream>>>(x, cb, xhi, cbhi, xsq, cbsq);
  const size_t smem = (size_t)BM * CDIM * 2 + (size_t)BNT * BK * 2;  // 147456 B
  vq_pass1<<<dim3(M_ROWS / BM, NSPLIT), 512, smem, stream>>>(xhi, cbhi, cbsq, srec);
  vq_finalize<<<M_ROWS / 4, 256, 0, stream>>>(x, cb, xsq, cbsq, srec,
                                              out + 8388608, out + 8421376, out);
}

// Round 8
// 290.295 us; speedup vs baseline: 1.3869x; 1.0580x over previous
//
#include <hip/hip_runtime.h>
#include <hip/hip_bf16.h>
#include <stdint.h>

// VQ nearest-codebook: B=8,N=4096,C=256,K=8192
// R8 = R6's proven 2-blocks/CU register structure (256 thr, acc[4][8], no spill)
//    + R7's A-residency (A staged ONCE -> FETCH 308->56 MB fix).
// 80 KB LDS/block (A 64 + B 16) = exactly 2 blocks/CU; the co-resident block
// hides each barrier's vmcnt(0) drain (R7 at 1 block/CU had nothing to overlap).
// hi-only fp16 GEMM + int-key top-2 records + exact fp32 margin finalize
// (record/finalize pipeline verified exact R3-R7: absmax=0 every round).

#define M_ROWS 32768   // B*N
#define KCODES 8192
#define CDIM   256
#define BM 128         // rows per block; A resident 128x256 fp16 = 64 KB
#define BNT 256        // codes per B tile
#define BK 32
#define NSPLIT 2
#define KCHUNK 4096    // codes per chunk (blockIdx.y)
#define NTILES 16      // KCHUNK / BNT
#define KSTEPS 8       // CDIM / BK
#define NREC 32        // records per row (each = top-2 over a 256-code subset)
#define MARGIN 0.75f   // >> hi-GEMM err (~0.32) + 2x key quantization (0.125)

typedef _Float16 f16x8 __attribute__((ext_vector_type(8)));
typedef _Float16 f16x4 __attribute__((ext_vector_type(4)));
typedef float    f32x4 __attribute__((ext_vector_type(4)));

__device__ __forceinline__ unsigned umin2(unsigned a, unsigned b) { return a < b ? a : b; }
__device__ __forceinline__ unsigned umax2(unsigned a, unsigned b) { return a > b ? a : b; }

// ---------------- prep: fp16 hi (scaled by 64) + row sq-norms ----------------
__global__ void vq_prep(const float* __restrict__ x, const float* __restrict__ cb,
                        _Float16* __restrict__ xhi, _Float16* __restrict__ cbhi,
                        float* __restrict__ xsq, float* __restrict__ cbsq) {
  const int wave = threadIdx.x >> 6, lane = threadIdx.x & 63;
  const int row = blockIdx.x * 4 + wave;     // one wave per row
  const float* src;
  _Float16* dhi;
  float* dsq;
  if (row < M_ROWS) {
    src = x + (size_t)row * CDIM;  dhi = xhi + (size_t)row * CDIM;  dsq = xsq + row;
  } else {
    const int r = row - M_ROWS;
    src = cb + (size_t)r * CDIM;   dhi = cbhi + (size_t)r * CDIM;   dsq = cbsq + r;
  }
  const float4 v = *(const float4*)(src + lane * 4);
  f16x4 h;
  h[0] = (_Float16)(v.x * 64.0f); h[1] = (_Float16)(v.y * 64.0f);
  h[2] = (_Float16)(v.z * 64.0f); h[3] = (_Float16)(v.w * 64.0f);
  *(f16x4*)(dhi + lane * 4) = h;
  float s = v.x * v.x + v.y * v.y + v.z * v.z + v.w * v.w;
  #pragma unroll
  for (int off = 32; off > 0; off >>= 1) s += __shfl_down(s, off, 64);
  if (lane == 0) *dsq = s;
}

// ---------------- pass1: A-resident hi GEMM + top-2 int-key records ----------------
__device__ __forceinline__ void gl16(const _Float16* g, _Float16* l) {
  __builtin_amdgcn_global_load_lds(
      (const __attribute__((address_space(1))) unsigned int*)g,
      (__attribute__((address_space(3))) unsigned int*)l, 16, 0, 0);
}

__global__ __launch_bounds__(256, 2) void vq_pass1(
    const _Float16* __restrict__ xhi, const _Float16* __restrict__ cbhi,
    const float* __restrict__ cbsq, uint2* __restrict__ srec) {
  extern __shared__ char smem[];
  _Float16* sA = (_Float16*)smem;                   // 128 x 256 fp16 = 64 KB
  _Float16* sB = (_Float16*)(smem + BM * CDIM * 2); // 256 x 32  fp16 = 16 KB

  const int tid  = threadIdx.x;
  const int wave = tid >> 6, lane = tid & 63;
  const int quad = lane >> 4, l15 = lane & 15;
  const int mbase  = blockIdx.x * BM;
  const int cbase0 = blockIdx.y * KCHUNK;
  const int wrow = (wave >> 1) * 64;    // row half
  const int wcol = (wave & 1) * 128;    // col half

  // ---- stage A once: row stride 512B = 32 x 16B slots; LDS(row,s)=Global(row,s^(row&7)).
  // Each gl16 covers 2 rows (64 lanes x 16B); 16 instrs per wave.
  {
    const int ar = lane >> 5;            // row within pair
    const int as = lane & 31;            // 16B slot
    #pragma unroll
    for (int t = 0; t < 16; ++t) {
      const int rb  = (wave * 16 + t) * 2;
      const int row = rb + ar;
      const int slot = as ^ (row & 7);
      gl16(xhi + (size_t)(mbase + row) * CDIM + slot * 8, sA + rb * CDIM);
    }
  }

  // B staging geometry (R2's measured-zero-conflict pattern): row stride 64B.
  const int srl  = lane >> 2;
  const int scol = (((lane & 3) ^ ((lane >> 3) & 3)) << 3);
  const int fcol = ((quad ^ ((l15 >> 1) & 3)) << 3);
  const int asw  = l15 & 7;             // A frag de-swizzle

  unsigned k1[4][4], k2[4][4];

  for (int nt = 0; nt < NTILES; ++nt) {
    const int cb0 = cbase0 + nt * BNT;
    if ((nt & 1) == 0) {   // open subchunk (per wave: 128 cols x 2 nt = 256 codes)
      #pragma unroll
      for (int mf = 0; mf < 4; ++mf)
        #pragma unroll
        for (int i = 0; i < 4; ++i) { k1[mf][i] = 0x7fffffffu; k2[mf][i] = 0x7fffffffu; }
    }

    f32x4 acc[4][8];
    #pragma unroll
    for (int mf = 0; mf < 4; ++mf)
      #pragma unroll
      for (int nf = 0; nf < 8; ++nf) {
        f32x4 z = {0.0f, 0.0f, 0.0f, 0.0f};
        acc[mf][nf] = z;
      }

    for (int ks = 0; ks < KSTEPS; ++ks) {
      const int kofs = ks * BK;
      __syncthreads();   // prior ks frag reads done (first iter: covers A staging too)
      // B: 16 slices of 16 rows -> 4 per wave
      #pragma unroll
      for (int t = 0; t < 4; ++t) {
        const int rb = wave * 64 + t * 16;
        gl16(cbhi + (size_t)(cb0 + rb + srl) * CDIM + kofs + scol, sB + rb * BK);
      }
      __syncthreads();   // staged data visible (drains A staging on first iter)

      f16x8 ah[4];
      #pragma unroll
      for (int mf = 0; mf < 4; ++mf) {
        const int arow = wrow + mf * 16 + l15;
        const int aslot = (ks * 4 + quad) ^ asw;       // 16B slot in resident A
        ah[mf] = *(const f16x8*)(sA + arow * CDIM + aslot * 8);
      }
      #pragma unroll
      for (int nf = 0; nf < 8; ++nf) {
        const f16x8 bh = *(const f16x8*)(sB + (wcol + nf * 16 + l15) * BK + fcol);
        #pragma unroll
        for (int mf = 0; mf < 4; ++mf)
          acc[mf][nf] = __builtin_amdgcn_mfma_f32_16x16x32_f16(ah[mf], bh, acc[mf][nf], 0, 0, 0);
      }
    }

    // int-key top-2 insert: key = (uint)(16*v + 32768) << 13 | col
    // v = cbsq - 2*dot; acc = 4096*dot => 16*v = (16*cbsq+32768) - acc/128
    #pragma unroll
    for (int nf = 0; nf < 8; ++nf) {
      const int col = cb0 + wcol + nf * 16 + l15;   // C/D: col = lane&15
      const float cq16 = fmaf(cbsq[col], 16.0f, 32768.0f);
      #pragma unroll
      for (int mf = 0; mf < 4; ++mf)
        #pragma unroll
        for (int i = 0; i < 4; ++i) {
          const float kf = fmaf(acc[mf][nf][i], -0.0078125f, cq16);
          const unsigned key = ((unsigned)kf << 13) | (unsigned)col;
          k2[mf][i] = umin2(k2[mf][i], umax2(k1[mf][i], key));
          k1[mf][i] = umin2(k1[mf][i], key);
        }
    }

    if (nt & 1) {   // close subchunk: 16-lane top-2 butterfly merge, store record
      const int g = blockIdx.y * 16 + (nt >> 1) * 2 + (wave & 1);  // 0..31
      #pragma unroll
      for (int mf = 0; mf < 4; ++mf)
        #pragma unroll
        for (int i = 0; i < 4; ++i) {
          unsigned a1 = k1[mf][i], a2 = k2[mf][i];
          #pragma unroll
          for (int m = 1; m <= 8; m <<= 1) {
            const unsigned o1 = (unsigned)__shfl_xor((int)a1, m, 64);
            const unsigned o2 = (unsigned)__shfl_xor((int)a2, m, 64);
            a2 = umin2(umin2(a2, o2), umax2(a1, o1));
            a1 = umin2(a1, o1);
          }
          if (l15 == 0) {
            const int rl = wrow + mf * 16 + quad * 4 + i;   // C/D row (0..127)
            uint2 r; r.x = a1; r.y = a2;
            srec[(size_t)(mbase + rl) * NREC + g] = r;
          }
        }
    }
  }
}

// ---------------- finalize: exact fp32 dots for margin candidates ----------------
__global__ void vq_finalize(const float* __restrict__ x, const float* __restrict__ cb,
                            const float* __restrict__ xsq, const float* __restrict__ cbsq,
                            const uint2* __restrict__ srec,
                            float* __restrict__ outIdx, float* __restrict__ outDist,
                            float* __restrict__ codes) {
  const int wave = threadIdx.x >> 6, lane = threadIdx.x & 63;
  const int row = blockIdx.x * 4 + wave;    // one wave per row
  uint2 rec;
  if (lane < NREC) rec = srec[(size_t)row * NREC + lane];
  else { rec.x = 0x7fffffffu; rec.y = 0x7fffffffu; }
  const float v1 = (float)(rec.x >> 13) * 0.0625f - 2048.0f;
  const float v2 = (float)(rec.y >> 13) * 0.0625f - 2048.0f;
  const int c1 = (int)(rec.x & 8191u);
  const int c2 = (int)(rec.y & 8191u);

  float gm = v1;
  #pragma unroll
  for (int m = 1; m <= 32; m <<= 1) gm = fminf(gm, __shfl_xor(gm, m, 64));
  const float thr = gm + MARGIN;
  unsigned long long mask1 = __ballot(v1 <= thr);
  unsigned long long mask2 = __ballot(v2 <= thr);

  const float4 xv = *(const float4*)(x + (size_t)row * CDIM + lane * 4);
  const float xq = xsq[row];
  float best = __builtin_inff(); int bidx = 1 << 30;

  #pragma unroll
  for (int pass = 0; pass < 2; ++pass) {
    unsigned long long m = pass ? mask2 : mask1;
    const int fi = pass ? c2 : c1;
    while (m) {
      const int g = __builtin_ctzll((long long)m); m &= m - 1;
      const int ci = __shfl(fi, g, 64);
      const float4 cv = *(const float4*)(cb + (size_t)ci * CDIM + lane * 4);
      float s = xv.x * cv.x + xv.y * cv.y + xv.z * cv.z + xv.w * cv.w;
      #pragma unroll
      for (int mm = 1; mm <= 32; mm <<= 1) s += __shfl_xor(s, mm, 64);
      const float dist = xq + cbsq[ci] - 2.0f * s;
      if (dist < best || (dist == best && ci < bidx)) { best = dist; bidx = ci; }
    }
  }

  if (lane == 0) { outIdx[row] = (float)bidx; outDist[row] = best; }
  const float4 cw = *(const float4*)(cb + (size_t)bidx * CDIM + lane * 4);
  *(float4*)(codes + (size_t)row * CDIM + lane * 4) = cw;
}

extern "C" void kernel_launch(void* const* d_in, const int* in_sizes, int n_in,
                              void* d_out, int out_size, void* d_ws, size_t ws_size,
                              hipStream_t stream) {
  const float* x  = (const float*)d_in[0];   // [8,4096,256] fp32
  const float* cb = (const float*)d_in[1];   // [8192,256] fp32
  float* out = (float*)d_out;                // codes | idx | dist

  char* w = (char*)d_ws;                     // ~29.2 MB
  _Float16* xhi  = (_Float16*)(w);                 // 16 MB
  _Float16* cbhi = (_Float16*)(w + 16777216);      //  4 MB
  float*    xsq  = (float*)   (w + 20971520);      // 128 KB
  float*    cbsq = (float*)   (w + 21102592);      //  32 KB
  uint2*    srec = (uint2*)   (w + 21135360);      //  8 MB (32768*32*8B)

  vq_prep<<<(M_ROWS + KCODES) / 4, 256, 0, stream>>>(x, cb, xhi, cbhi, xsq, cbsq);
  const size_t smem = (size_t)BM * CDIM * 2 + (size_t)BNT * BK * 2;  // 81920 B
  vq_pass1<<<dim3(M_ROWS / BM, NSPLIT), 256, smem, stream>>>(xhi, cbhi, cbsq, srec);
  vq_finalize<<<M_ROWS / 4, 256, 0, stream>>>(x, cb, xsq, cbsq, srec,
                                              out + 8388608, out + 8421376, out);
}